// Round 1
// baseline (1191.257 us; speedup 1.0000x reference)
//
#include <hip/hip_runtime.h>

typedef __bf16 bf16;
typedef __bf16 bf16x8 __attribute__((ext_vector_type(8)));
typedef __bf16 bf16x4v __attribute__((ext_vector_type(4)));
typedef float f32x4 __attribute__((ext_vector_type(4)));

#define D_   1024
#define S_   1024
#define B_   2
#define NTOK 2048       // B*S
#define FF_  4096
#define NE   8
#define CAP  5120       // padded slot capacity (4096 assignments + per-expert pad to 128)
#define OUTN 2097152    // B*S*D

__device__ __forceinline__ float gelu_f(float x) {
    return 0.5f * x * (1.0f + tanhf(0.7978845608028654f * (x + 0.044715f * x * x * x)));
}

// ---------------------------------------------------------------------------
// RMSNorm: one block per row of 1024. Optional fp32 and bf16 outputs.
// ---------------------------------------------------------------------------
__global__ __launch_bounds__(256) void rmsnorm_k(const float* __restrict__ x,
                                                 const float* __restrict__ w,
                                                 float* __restrict__ yf,
                                                 bf16* __restrict__ yb) {
    int row = blockIdx.x;
    int t = threadIdx.x;
    const float* xr = x + (size_t)row * D_;
    float4 v = *(const float4*)(xr + t * 4);
    float ss = v.x * v.x + v.y * v.y + v.z * v.z + v.w * v.w;
    for (int off = 32; off; off >>= 1) ss += __shfl_down(ss, off);
    __shared__ float wsum[4];
    if ((t & 63) == 0) wsum[t >> 6] = ss;
    __syncthreads();
    float tot = wsum[0] + wsum[1] + wsum[2] + wsum[3];
    float rr = rsqrtf(tot * (1.0f / D_) + 1e-6f);
    float4 wv = *(const float4*)(w + t * 4);
    float4 y;
    y.x = v.x * rr * wv.x; y.y = v.y * rr * wv.y;
    y.z = v.z * rr * wv.z; y.w = v.w * rr * wv.w;
    if (yf) *(float4*)(yf + (size_t)row * D_ + t * 4) = y;
    if (yb) {
        bf16x4v bv = { (bf16)y.x, (bf16)y.y, (bf16)y.z, (bf16)y.w };
        *(bf16x4v*)(yb + (size_t)row * D_ + t * 4) = bv;
    }
}

// ---------------------------------------------------------------------------
// fp32 dense GEMM, 128x128 tile, BK=16, 256 threads, 8x8 per thread.
// C = A(2048x1024) @ B(1024x1024); optional epilogue add X.
// ---------------------------------------------------------------------------
#define FLDS 132

__device__ __forceinline__ void gemm128_body(const float* __restrict__ A,
                                             const float* __restrict__ B,
                                             float* __restrict__ C,
                                             const float* __restrict__ X,
                                             float* As, float* Bs) {
    int t = threadIdx.x;
    int m0 = blockIdx.x * 128, n0 = blockIdx.y * 128;
    int tx = t & 15, ty = t >> 4;
    float acc[8][8];
#pragma unroll
    for (int i = 0; i < 8; i++)
#pragma unroll
        for (int j = 0; j < 8; j++) acc[i][j] = 0.0f;

    int am = t >> 1;
    int ak = (t & 1) * 8;
    int bk = t >> 4;
    int bn = (t & 15) * 8;

    for (int k0 = 0; k0 < 1024; k0 += 16) {
        __syncthreads();
        float4 a0 = *(const float4*)(A + (size_t)(m0 + am) * 1024 + k0 + ak);
        float4 a1 = *(const float4*)(A + (size_t)(m0 + am) * 1024 + k0 + ak + 4);
        As[(ak + 0) * FLDS + am] = a0.x; As[(ak + 1) * FLDS + am] = a0.y;
        As[(ak + 2) * FLDS + am] = a0.z; As[(ak + 3) * FLDS + am] = a0.w;
        As[(ak + 4) * FLDS + am] = a1.x; As[(ak + 5) * FLDS + am] = a1.y;
        As[(ak + 6) * FLDS + am] = a1.z; As[(ak + 7) * FLDS + am] = a1.w;
        float4 b0 = *(const float4*)(B + (size_t)(k0 + bk) * 1024 + n0 + bn);
        float4 b1 = *(const float4*)(B + (size_t)(k0 + bk) * 1024 + n0 + bn + 4);
        *(float4*)&Bs[bk * FLDS + bn] = b0;
        *(float4*)&Bs[bk * FLDS + bn + 4] = b1;
        __syncthreads();
#pragma unroll
        for (int d = 0; d < 16; d++) {
            float4 x0 = *(float4*)&As[d * FLDS + ty * 8];
            float4 x1 = *(float4*)&As[d * FLDS + ty * 8 + 4];
            float4 y0 = *(float4*)&Bs[d * FLDS + tx * 8];
            float4 y1 = *(float4*)&Bs[d * FLDS + tx * 8 + 4];
            float xa[8] = {x0.x, x0.y, x0.z, x0.w, x1.x, x1.y, x1.z, x1.w};
            float yb[8] = {y0.x, y0.y, y0.z, y0.w, y1.x, y1.y, y1.z, y1.w};
#pragma unroll
            for (int i = 0; i < 8; i++)
#pragma unroll
                for (int j = 0; j < 8; j++)
                    acc[i][j] = fmaf(xa[i], yb[j], acc[i][j]);
        }
    }
#pragma unroll
    for (int i = 0; i < 8; i++) {
        size_t roff = (size_t)(m0 + ty * 8 + i) * 1024 + n0 + tx * 8;
#pragma unroll
        for (int jq = 0; jq < 8; jq += 4) {
            float4 c4 = {acc[i][jq], acc[i][jq + 1], acc[i][jq + 2], acc[i][jq + 3]};
            if (X) {
                float4 xv = *(const float4*)(X + roff + jq);
                c4.x += xv.x; c4.y += xv.y; c4.z += xv.z; c4.w += xv.w;
            }
            *(float4*)(C + roff + jq) = c4;
        }
    }
}

__global__ __launch_bounds__(256) void gemm_qkv_k(const float* __restrict__ A,
    const float* __restrict__ Bq, const float* __restrict__ Bk, const float* __restrict__ Bv,
    float* __restrict__ Cq, float* __restrict__ Ck, float* __restrict__ Cv) {
    __shared__ float As[16 * FLDS];
    __shared__ float Bs[16 * FLDS];
    const float* B = (blockIdx.z == 0) ? Bq : (blockIdx.z == 1) ? Bk : Bv;
    float* C = (blockIdx.z == 0) ? Cq : (blockIdx.z == 1) ? Ck : Cv;
    gemm128_body(A, B, C, nullptr, As, Bs);
}

__global__ __launch_bounds__(256) void gemm_wo_k(const float* __restrict__ A,
    const float* __restrict__ B, float* __restrict__ C, const float* __restrict__ X) {
    __shared__ float As[16 * FLDS];
    __shared__ float Bs[16 * FLDS];
    gemm128_body(A, B, C, X, As, Bs);
}

// ---------------------------------------------------------------------------
// fp32 flash attention. Block = (qt, h, b), 64 q-rows, 256 threads.
// Thread (tx,ty) owns 4 q-rows (ty*4+i) x 4 cols (tx*4+j).
// ---------------------------------------------------------------------------
#define ALDS 68

__global__ __launch_bounds__(256) void attn_f32_k(const float* __restrict__ q,
                                                  const float* __restrict__ kbuf,
                                                  const float* __restrict__ vbuf,
                                                  float* __restrict__ o) {
    int qt = blockIdx.x, h = blockIdx.y, b = blockIdx.z;
    __shared__ float Qt[64 * ALDS];   // [d][q]
    __shared__ float KPt[64 * ALDS];  // [d][kpos] then reused as P [kpos][q]
    __shared__ float Vs[64 * ALDS];   // [kpos][d]
    int t = threadIdx.x, tx = t & 15, ty = t >> 4;
    int sr = t >> 2, sq = (t & 3) * 16;

    {
        const float* qp = q + ((size_t)(b * S_ + qt * 64 + sr)) * D_ + h * 64 + sq;
#pragma unroll
        for (int c = 0; c < 4; c++) {
            float4 v4 = *(const float4*)(qp + c * 4);
            Qt[(sq + c * 4 + 0) * ALDS + sr] = v4.x;
            Qt[(sq + c * 4 + 1) * ALDS + sr] = v4.y;
            Qt[(sq + c * 4 + 2) * ALDS + sr] = v4.z;
            Qt[(sq + c * 4 + 3) * ALDS + sr] = v4.w;
        }
    }

    float mrow[4], lrow[4], O[4][4];
#pragma unroll
    for (int i = 0; i < 4; i++) {
        mrow[i] = -1e30f; lrow[i] = 0.0f;
#pragma unroll
        for (int j = 0; j < 4; j++) O[i][j] = 0.0f;
    }

    for (int kt = 0; kt <= qt; kt++) {
        __syncthreads();
        {
            const float* kp = kbuf + ((size_t)(b * S_ + kt * 64 + sr)) * D_ + h * 64 + sq;
            const float* vp = vbuf + ((size_t)(b * S_ + kt * 64 + sr)) * D_ + h * 64 + sq;
#pragma unroll
            for (int c = 0; c < 4; c++) {
                float4 v4 = *(const float4*)(kp + c * 4);
                KPt[(sq + c * 4 + 0) * ALDS + sr] = v4.x;
                KPt[(sq + c * 4 + 1) * ALDS + sr] = v4.y;
                KPt[(sq + c * 4 + 2) * ALDS + sr] = v4.z;
                KPt[(sq + c * 4 + 3) * ALDS + sr] = v4.w;
                float4 w4 = *(const float4*)(vp + c * 4);
                *(float4*)&Vs[sr * ALDS + sq + c * 4] = w4;
            }
        }
        __syncthreads();

        float s[4][4];
#pragma unroll
        for (int i = 0; i < 4; i++)
#pragma unroll
            for (int j = 0; j < 4; j++) s[i][j] = 0.0f;
        for (int d = 0; d < 64; d++) {
            float4 q4 = *(float4*)&Qt[d * ALDS + ty * 4];
            float4 k4 = *(float4*)&KPt[d * ALDS + tx * 4];
            float qa[4] = {q4.x, q4.y, q4.z, q4.w};
            float ka[4] = {k4.x, k4.y, k4.z, k4.w};
#pragma unroll
            for (int i = 0; i < 4; i++)
#pragma unroll
                for (int j = 0; j < 4; j++)
                    s[i][j] = fmaf(qa[i], ka[j], s[i][j]);
        }
        bool diag = (kt == qt);
#pragma unroll
        for (int i = 0; i < 4; i++)
#pragma unroll
            for (int j = 0; j < 4; j++) {
                s[i][j] *= 0.125f;  // 1/sqrt(64)
                if (diag && (tx * 4 + j) > (ty * 4 + i)) s[i][j] = -1e30f;
            }

        float p[4][4], alpha[4];
#pragma unroll
        for (int i = 0; i < 4; i++) {
            float tm = fmaxf(fmaxf(s[i][0], s[i][1]), fmaxf(s[i][2], s[i][3]));
            for (int off = 1; off < 16; off <<= 1) tm = fmaxf(tm, __shfl_xor(tm, off, 16));
            float mnew = fmaxf(mrow[i], tm);
            alpha[i] = expf(mrow[i] - mnew);
            float rs = 0.0f;
#pragma unroll
            for (int j = 0; j < 4; j++) { p[i][j] = expf(s[i][j] - mnew); rs += p[i][j]; }
            for (int off = 1; off < 16; off <<= 1) rs += __shfl_xor(rs, off, 16);
            lrow[i] = lrow[i] * alpha[i] + rs;
            mrow[i] = mnew;
#pragma unroll
            for (int j = 0; j < 4; j++) O[i][j] *= alpha[i];
        }

        __syncthreads();  // everyone done reading K-tile
#pragma unroll
        for (int i = 0; i < 4; i++)
#pragma unroll
            for (int j = 0; j < 4; j++)
                KPt[(tx * 4 + j) * ALDS + ty * 4 + i] = p[i][j];  // P[kpos][q]
        __syncthreads();

        for (int kp2 = 0; kp2 < 64; kp2++) {
            float4 pr = *(float4*)&KPt[kp2 * ALDS + ty * 4];
            float4 vr = *(float4*)&Vs[kp2 * ALDS + tx * 4];
            float pa[4] = {pr.x, pr.y, pr.z, pr.w};
            float va[4] = {vr.x, vr.y, vr.z, vr.w};
#pragma unroll
            for (int i = 0; i < 4; i++)
#pragma unroll
                for (int j = 0; j < 4; j++)
                    O[i][j] = fmaf(pa[i], va[j], O[i][j]);
        }
    }

#pragma unroll
    for (int i = 0; i < 4; i++) {
        float inv = 1.0f / lrow[i];
        float4 o4 = {O[i][0] * inv, O[i][1] * inv, O[i][2] * inv, O[i][3] * inv};
        *(float4*)(o + ((size_t)(b * S_ + qt * 64 + ty * 4 + i)) * D_ + h * 64 + tx * 4) = o4;
    }
}

// ---------------------------------------------------------------------------
// Router: 4 tokens/block (wave each). fp32 logits -> softmax -> top2.
// ---------------------------------------------------------------------------
__global__ __launch_bounds__(256) void router_k(const float* __restrict__ h,
                                                const float* __restrict__ rw,
                                                int* __restrict__ tidx,
                                                float* __restrict__ tgate,
                                                int* __restrict__ ecnt,
                                                float* __restrict__ psum) {
    int wv = threadIdx.x >> 6, ln = threadIdx.x & 63;
    int tok = blockIdx.x * 4 + wv;
    const float* hr = h + (size_t)tok * D_;
    float acc[NE];
#pragma unroll
    for (int e = 0; e < NE; e++) acc[e] = 0.0f;
    int base = ln * 16;
#pragma unroll
    for (int c = 0; c < 4; c++) {
        float4 hv = *(const float4*)(hr + base + c * 4);
        const float* rp = rw + (size_t)(base + c * 4) * NE;
        float hx[4] = {hv.x, hv.y, hv.z, hv.w};
#pragma unroll
        for (int jj = 0; jj < 4; jj++)
#pragma unroll
            for (int e = 0; e < NE; e++)
                acc[e] = fmaf(hx[jj], rp[jj * NE + e], acc[e]);
    }
#pragma unroll
    for (int e = 0; e < NE; e++)
        for (int off = 32; off; off >>= 1) acc[e] += __shfl_down(acc[e], off);

    __shared__ float pb[4][NE];
    if (ln == 0) {
        float mx = acc[0];
#pragma unroll
        for (int e = 1; e < NE; e++) mx = fmaxf(mx, acc[e]);
        float p[NE], ssum = 0.0f;
#pragma unroll
        for (int e = 0; e < NE; e++) { p[e] = expf(acc[e] - mx); ssum += p[e]; }
        float inv = 1.0f / ssum;
#pragma unroll
        for (int e = 0; e < NE; e++) p[e] *= inv;
        int i0 = 0; float b0 = p[0];
#pragma unroll
        for (int e = 1; e < NE; e++) if (p[e] > b0) { b0 = p[e]; i0 = e; }
        int i1 = -1; float b1v = -1.0f;
#pragma unroll
        for (int e = 0; e < NE; e++) if (e != i0 && p[e] > b1v) { b1v = p[e]; i1 = e; }
        tidx[tok * 2] = i0; tidx[tok * 2 + 1] = i1;
        tgate[tok * 2] = b0; tgate[tok * 2 + 1] = b1v;
        atomicAdd(&ecnt[i0], 1);
        atomicAdd(&ecnt[i1], 1);
#pragma unroll
        for (int e = 0; e < NE; e++) pb[wv][e] = p[e];
    }
    __syncthreads();
    if (threadIdx.x < NE) {
        float s2 = pb[0][threadIdx.x] + pb[1][threadIdx.x] + pb[2][threadIdx.x] + pb[3][threadIdx.x];
        atomicAdd(&psum[threadIdx.x], s2);
    }
}

__global__ void passb_k(const int* __restrict__ ecnt, const float* __restrict__ psum,
                        int* __restrict__ eoffp, int* __restrict__ ecnt2,
                        float* __restrict__ out_tail) {
    if (threadIdx.x == 0) {
        int off = 0; float loss = 0.0f;
        for (int e = 0; e < NE; e++) {
            eoffp[e] = off;
            int c = ecnt[e];
            off += (c + 127) & ~127;
            loss += (c * (1.0f / 4096.0f)) * (psum[e] * (1.0f / 2048.0f));
            out_tail[1 + e] = (float)c;
            ecnt2[e] = 0;
        }
        eoffp[NE] = off;
        out_tail[0] = 8.0f * loss;
    }
}

__global__ __launch_bounds__(256) void scatter_k(const int* __restrict__ tidx,
                                                 const float* __restrict__ tgate,
                                                 const int* __restrict__ eoffp,
                                                 int* __restrict__ ecnt2,
                                                 int* __restrict__ stok,
                                                 float* __restrict__ sgate) {
    int tok = blockIdx.x * 256 + threadIdx.x;
    for (int k = 0; k < 2; k++) {
        int e = tidx[tok * 2 + k];
        int pos = eoffp[e] + atomicAdd(&ecnt2[e], 1);
        stok[pos] = tok;
        sgate[pos] = tgate[tok * 2 + k];
    }
}

// ---------------------------------------------------------------------------
// Transpose + cast fp32 -> bf16: in [z][R][C] -> out [z][C][R]
// ---------------------------------------------------------------------------
__global__ __launch_bounds__(256) void transpose_cast_k(const float* __restrict__ in,
                                                        bf16* __restrict__ out,
                                                        int R, int C) {
    __shared__ float tl[32][33];
    size_t base = (size_t)blockIdx.z * R * C;
    const float* src = in + base;
    bf16* dst = out + base;
    int c0 = blockIdx.x * 32, r0 = blockIdx.y * 32;
    int tx = threadIdx.x & 31, tyy = threadIdx.x >> 5;
#pragma unroll
    for (int i = 0; i < 4; i++) {
        int r = tyy + i * 8;
        tl[r][tx] = src[(size_t)(r0 + r) * C + c0 + tx];
    }
    __syncthreads();
#pragma unroll
    for (int i = 0; i < 4; i++) {
        int c = tyy + i * 8;
        dst[(size_t)(c0 + c) * R + r0 + tx] = (bf16)tl[tx][c];
    }
}

// ---------------------------------------------------------------------------
// MoE MFMA GEMMs: 128x128 tile, BK=32, 4 waves (2x2), each wave 64x64 (4x4 frags)
// LDS stride 40 (pad 8) -> conflict-free-ish b128 frag reads.
// ---------------------------------------------------------------------------
#define MLD 40

__global__ __launch_bounds__(256) void moe_gemm1_k(const bf16* __restrict__ hB,
                                                   const bf16* __restrict__ w1t,
                                                   const float* __restrict__ b1,
                                                   const int* __restrict__ eoffp,
                                                   const int* __restrict__ stok,
                                                   bf16* __restrict__ act) {
    int m0 = blockIdx.x * 128, n0 = blockIdx.y * 128;
    if (m0 >= eoffp[NE]) return;
    int e = 0;
#pragma unroll
    for (int i = 1; i < NE; i++) if (m0 >= eoffp[i]) e = i;

    __shared__ bf16 As[128 * MLD];
    __shared__ bf16 Bs[128 * MLD];
    __shared__ int tok_l[128];
    int t = threadIdx.x;
    if (t < 128) tok_l[t] = stok[m0 + t];

    int wv = t >> 6, ln = t & 63;
    int wm = wv >> 1, wn = wv & 1;
    int lane15 = ln & 15, quad = ln >> 4;
    f32x4 acc[4][4];
#pragma unroll
    for (int mt = 0; mt < 4; mt++)
#pragma unroll
        for (int nt = 0; nt < 4; nt++) acc[mt][nt] = (f32x4){0.f, 0.f, 0.f, 0.f};

    const bf16* Bbase = w1t + ((size_t)e * FF_ + n0) * D_;

    for (int k0 = 0; k0 < D_; k0 += 32) {
        __syncthreads();
#pragma unroll
        for (int j = 0; j < 2; j++) {
            int idx = t + j * 256;
            int row = idx >> 2, kc = (idx & 3) * 8;
            uint4 av = *(const uint4*)(hB + (size_t)tok_l[row] * D_ + k0 + kc);
            *(uint4*)&As[row * MLD + kc] = av;
            uint4 bv = *(const uint4*)(Bbase + (size_t)row * D_ + k0 + kc);
            *(uint4*)&Bs[row * MLD + kc] = bv;
        }
        __syncthreads();
        bf16x8 af[4], bfr[4];
#pragma unroll
        for (int mt = 0; mt < 4; mt++)
            af[mt] = *(const bf16x8*)&As[(wm * 64 + mt * 16 + lane15) * MLD + quad * 8];
#pragma unroll
        for (int nt = 0; nt < 4; nt++)
            bfr[nt] = *(const bf16x8*)&Bs[(wn * 64 + nt * 16 + lane15) * MLD + quad * 8];
#pragma unroll
        for (int mt = 0; mt < 4; mt++)
#pragma unroll
            for (int nt = 0; nt < 4; nt++)
                acc[mt][nt] = __builtin_amdgcn_mfma_f32_16x16x32_bf16(af[mt], bfr[nt], acc[mt][nt], 0, 0, 0);
    }

    const float* b1e = b1 + (size_t)e * FF_;
#pragma unroll
    for (int mt = 0; mt < 4; mt++)
#pragma unroll
        for (int nt = 0; nt < 4; nt++) {
            int gn = n0 + wn * 64 + nt * 16 + lane15;
            float bias = b1e[gn];
#pragma unroll
            for (int r = 0; r < 4; r++) {
                int gm = m0 + wm * 64 + mt * 16 + quad * 4 + r;
                float vv = acc[mt][nt][r] + bias;
                act[(size_t)gm * FF_ + gn] = (bf16)gelu_f(vv);
            }
        }
}

__global__ __launch_bounds__(256) void moe_gemm2_k(const bf16* __restrict__ act,
                                                   const bf16* __restrict__ w2t,
                                                   const float* __restrict__ b2,
                                                   const int* __restrict__ eoffp,
                                                   const int* __restrict__ stok,
                                                   const float* __restrict__ sgate,
                                                   float* __restrict__ out) {
    int m0 = blockIdx.x * 128, n0 = blockIdx.y * 128;
    if (m0 >= eoffp[NE]) return;
    int e = 0;
#pragma unroll
    for (int i = 1; i < NE; i++) if (m0 >= eoffp[i]) e = i;

    __shared__ bf16 As[128 * MLD];
    __shared__ bf16 Bs[128 * MLD];
    __shared__ int tok_l[128];
    __shared__ float gate_l[128];
    int t = threadIdx.x;
    if (t < 128) { tok_l[t] = stok[m0 + t]; gate_l[t] = sgate[m0 + t]; }

    int wv = t >> 6, ln = t & 63;
    int wm = wv >> 1, wn = wv & 1;
    int lane15 = ln & 15, quad = ln >> 4;
    f32x4 acc[4][4];
#pragma unroll
    for (int mt = 0; mt < 4; mt++)
#pragma unroll
        for (int nt = 0; nt < 4; nt++) acc[mt][nt] = (f32x4){0.f, 0.f, 0.f, 0.f};

    const bf16* Bbase = w2t + ((size_t)e * D_ + n0) * FF_;

    for (int k0 = 0; k0 < FF_; k0 += 32) {
        __syncthreads();
#pragma unroll
        for (int j = 0; j < 2; j++) {
            int idx = t + j * 256;
            int row = idx >> 2, kc = (idx & 3) * 8;
            uint4 av = *(const uint4*)(act + (size_t)(m0 + row) * FF_ + k0 + kc);
            *(uint4*)&As[row * MLD + kc] = av;
            uint4 bv = *(const uint4*)(Bbase + (size_t)row * FF_ + k0 + kc);
            *(uint4*)&Bs[row * MLD + kc] = bv;
        }
        __syncthreads();
        bf16x8 af[4], bfr[4];
#pragma unroll
        for (int mt = 0; mt < 4; mt++)
            af[mt] = *(const bf16x8*)&As[(wm * 64 + mt * 16 + lane15) * MLD + quad * 8];
#pragma unroll
        for (int nt = 0; nt < 4; nt++)
            bfr[nt] = *(const bf16x8*)&Bs[(wn * 64 + nt * 16 + lane15) * MLD + quad * 8];
#pragma unroll
        for (int mt = 0; mt < 4; mt++)
#pragma unroll
            for (int nt = 0; nt < 4; nt++)
                acc[mt][nt] = __builtin_amdgcn_mfma_f32_16x16x32_bf16(af[mt], bfr[nt], acc[mt][nt], 0, 0, 0);
    }

    const float* b2e = b2 + (size_t)e * D_;
#pragma unroll
    for (int mt = 0; mt < 4; mt++)
#pragma unroll
        for (int nt = 0; nt < 4; nt++) {
            int gn = n0 + wn * 64 + nt * 16 + lane15;
            float bias = b2e[gn];
#pragma unroll
            for (int r = 0; r < 4; r++) {
                int lm = wm * 64 + mt * 16 + quad * 4 + r;
                int tok = tok_l[lm];
                float g = gate_l[lm];
                atomicAdd(out + (size_t)tok * D_ + gn, g * (acc[mt][nt][r] + bias));
            }
        }
}

// ---------------------------------------------------------------------------
extern "C" void kernel_launch(void* const* d_in, const int* in_sizes, int n_in,
                              void* d_out, int out_size, void* d_ws, size_t ws_size,
                              hipStream_t stream) {
    const float* x   = (const float*)d_in[0];
    const float* anw = (const float*)d_in[1];
    const float* wq  = (const float*)d_in[2];
    const float* wk  = (const float*)d_in[3];
    const float* wv  = (const float*)d_in[4];
    const float* wo  = (const float*)d_in[5];
    const float* mnw = (const float*)d_in[6];
    const float* rw  = (const float*)d_in[7];
    const float* w1  = (const float*)d_in[8];
    const float* b1  = (const float*)d_in[9];
    const float* w2  = (const float*)d_in[10];
    const float* b2  = (const float*)d_in[11];
    float* out = (float*)d_out;

    char* p = (char*)d_ws;
    auto take = [&](size_t n) { char* r = p; p += (n + 255) & ~(size_t)255; return r; };
    float* q_f   = (float*)take((size_t)OUTN * 4);
    float* k_f   = (float*)take((size_t)OUTN * 4);
    float* v_f   = (float*)take((size_t)OUTN * 4);
    float* h1_f  = (float*)take((size_t)OUTN * 4);
    float* ao_f  = (float*)take((size_t)OUTN * 4);
    float* h_f   = (float*)take((size_t)OUTN * 4);
    bf16*  h_b   = (bf16*)take((size_t)OUTN * 2);
    bf16*  w1t   = (bf16*)take((size_t)NE * FF_ * D_ * 2);
    bf16*  w2t   = (bf16*)take((size_t)NE * FF_ * D_ * 2);
    bf16*  act   = (bf16*)take((size_t)CAP * FF_ * 2);
    int*   tidx  = (int*)take(NTOK * 2 * 4);
    float* tgate = (float*)take(NTOK * 2 * 4);
    int*   ecnt  = (int*)take(64);
    int*   ecnt2 = (int*)take(64);
    float* psum  = (float*)take(64);
    int*   eoffp = (int*)take(64);
    int*   stok  = (int*)take(CAP * 4);
    float* sgate = (float*)take(CAP * 4);

    hipMemsetAsync(ecnt, 0, NE * 4, stream);
    hipMemsetAsync(psum, 0, NE * 4, stream);
    hipMemsetAsync(stok, 0, CAP * 4, stream);
    hipMemsetAsync(sgate, 0, CAP * 4, stream);

    // weight transpose-casts (bf16, [E][N][K] so B stages k-contiguous)
    transpose_cast_k<<<dim3(FF_ / 32, D_ / 32, NE), 256, 0, stream>>>(w1, w1t, D_, FF_);
    transpose_cast_k<<<dim3(D_ / 32, FF_ / 32, NE), 256, 0, stream>>>(w2, w2t, FF_, D_);

    // attention path (fp32 for router-input fidelity)
    rmsnorm_k<<<NTOK, 256, 0, stream>>>(x, anw, h1_f, nullptr);
    gemm_qkv_k<<<dim3(16, 8, 3), 256, 0, stream>>>(h1_f, wq, wk, wv, q_f, k_f, v_f);
    attn_f32_k<<<dim3(16, 16, 2), 256, 0, stream>>>(q_f, k_f, v_f, ao_f);
    gemm_wo_k<<<dim3(16, 8), 256, 0, stream>>>(ao_f, wo, out, x);   // out = x + ao@wo (residual)

    // MoE
    rmsnorm_k<<<NTOK, 256, 0, stream>>>(out, mnw, h_f, h_b);
    router_k<<<NTOK / 4, 256, 0, stream>>>(h_f, rw, tidx, tgate, ecnt, psum);
    passb_k<<<1, 64, 0, stream>>>(ecnt, psum, eoffp, ecnt2, out + OUTN);
    scatter_k<<<NTOK / 256, 256, 0, stream>>>(tidx, tgate, eoffp, ecnt2, stok, sgate);
    moe_gemm1_k<<<dim3(CAP / 128, FF_ / 128), 256, 0, stream>>>(h_b, w1t, b1, eoffp, stok, act);
    moe_gemm2_k<<<dim3(CAP / 128, D_ / 128), 256, 0, stream>>>(act, w2t, b2, eoffp, stok, sgate, out);
}

// Round 2
// 900.090 us; speedup vs baseline: 1.3235x; 1.3235x over previous
//
#include <hip/hip_runtime.h>

typedef __bf16 bf16;
typedef __bf16 bf16x8 __attribute__((ext_vector_type(8)));
typedef float f32x4 __attribute__((ext_vector_type(4)));

#define D_   1024
#define S_   1024
#define B_   2
#define NTOK 2048
#define FF_  4096
#define NE   8
#define CAP  5120
#define OUTN 2097152

__device__ __forceinline__ float gelu_f(float x) {
    return 0.5f * x * (1.0f + tanhf(0.7978845608028654f * (x + 0.044715f * x * x * x)));
}

// ---------------------------------------------------------------------------
// RMSNorm: one block per row of 1024. Optional fp32 / split-bf16 outputs.
// ---------------------------------------------------------------------------
__global__ __launch_bounds__(256) void rmsnorm_k(const float* __restrict__ x,
                                                 const float* __restrict__ w,
                                                 float* __restrict__ yf,
                                                 bf16* __restrict__ yhi,
                                                 bf16* __restrict__ ylo) {
    int row = blockIdx.x;
    int t = threadIdx.x;
    const float* xr = x + (size_t)row * D_;
    float4 v = *(const float4*)(xr + t * 4);
    float ss = v.x * v.x + v.y * v.y + v.z * v.z + v.w * v.w;
    for (int off = 32; off; off >>= 1) ss += __shfl_down(ss, off);
    __shared__ float wsum[4];
    if ((t & 63) == 0) wsum[t >> 6] = ss;
    __syncthreads();
    float tot = wsum[0] + wsum[1] + wsum[2] + wsum[3];
    float rr = rsqrtf(tot * (1.0f / D_) + 1e-6f);
    float4 wv = *(const float4*)(w + t * 4);
    float y[4];
    y[0] = v.x * rr * wv.x; y[1] = v.y * rr * wv.y;
    y[2] = v.z * rr * wv.z; y[3] = v.w * rr * wv.w;
    if (yf) *(float4*)(yf + (size_t)row * D_ + t * 4) = *(float4*)y;
    if (yhi) {
#pragma unroll
        for (int i = 0; i < 4; i++) {
            bf16 hi = (bf16)y[i];
            yhi[(size_t)row * D_ + t * 4 + i] = hi;
            if (ylo) ylo[(size_t)row * D_ + t * 4 + i] = (bf16)(y[i] - (float)hi);
        }
    }
}

// ---------------------------------------------------------------------------
// Transpose + split-cast fp32 [1024][1024] (K-major) -> bf16 hi/lo [N][K].
// z selects one of the 4 attention weights.
// ---------------------------------------------------------------------------
__global__ __launch_bounds__(256) void trans_split_k(
    const float* __restrict__ w0, const float* __restrict__ w1p,
    const float* __restrict__ w2p, const float* __restrict__ w3,
    bf16* o0h, bf16* o0l, bf16* o1h, bf16* o1l,
    bf16* o2h, bf16* o2l, bf16* o3h, bf16* o3l) {
    int z = blockIdx.z;
    const float* src = (z == 0) ? w0 : (z == 1) ? w1p : (z == 2) ? w2p : w3;
    bf16* dh = (z == 0) ? o0h : (z == 1) ? o1h : (z == 2) ? o2h : o3h;
    bf16* dl = (z == 0) ? o0l : (z == 1) ? o1l : (z == 2) ? o2l : o3l;
    __shared__ float tl[32][33];
    int c0 = blockIdx.x * 32, r0 = blockIdx.y * 32;
    int tx = threadIdx.x & 31, ty = threadIdx.x >> 5;
#pragma unroll
    for (int i = 0; i < 4; i++) {
        int r = ty + i * 8;
        tl[r][tx] = src[(size_t)(r0 + r) * 1024 + c0 + tx];
    }
    __syncthreads();
#pragma unroll
    for (int i = 0; i < 4; i++) {
        int c = ty + i * 8;
        float v = tl[tx][c];
        bf16 hi = (bf16)v;
        dh[(size_t)(c0 + c) * 1024 + r0 + tx] = hi;
        dl[(size_t)(c0 + c) * 1024 + r0 + tx] = (bf16)(v - (float)hi);
    }
}

// ---------------------------------------------------------------------------
// Transpose + cast fp32 -> bf16: in [z][R][C] -> out [z][C][R]  (MoE weights)
// ---------------------------------------------------------------------------
__global__ __launch_bounds__(256) void transpose_cast_k(const float* __restrict__ in,
                                                        bf16* __restrict__ out,
                                                        int R, int C) {
    __shared__ float tl[32][33];
    size_t base = (size_t)blockIdx.z * R * C;
    const float* src = in + base;
    bf16* dst = out + base;
    int c0 = blockIdx.x * 32, r0 = blockIdx.y * 32;
    int tx = threadIdx.x & 31, tyy = threadIdx.x >> 5;
#pragma unroll
    for (int i = 0; i < 4; i++) {
        int r = tyy + i * 8;
        tl[r][tx] = src[(size_t)(r0 + r) * C + c0 + tx];
    }
    __syncthreads();
#pragma unroll
    for (int i = 0; i < 4; i++) {
        int c = tyy + i * 8;
        dst[(size_t)(c0 + c) * R + r0 + tx] = (bf16)tl[tx][c];
    }
}

// ---------------------------------------------------------------------------
// Split-bf16 dense GEMM, 128x128 tile, BK=32, 4 waves 2x2, 3 MFMA products.
// A [M][K] hi/lo, B [N][K] hi/lo (pre-transposed), K=1024.
// ---------------------------------------------------------------------------
#define GLD 40

#define GEMM_SPLIT_BODY(EPILOGUE)                                                     \
    __shared__ bf16 Ash[128 * GLD], Asl[128 * GLD], Bsh[128 * GLD], Bsl[128 * GLD];   \
    int t = threadIdx.x;                                                              \
    int m0 = blockIdx.x * 128, n0 = blockIdx.y * 128;                                 \
    int wv = t >> 6, ln = t & 63, wm = wv >> 1, wn = wv & 1;                          \
    int l15 = ln & 15, qd = ln >> 4;                                                  \
    f32x4 acc[4][4];                                                                  \
    _Pragma("unroll") for (int mt = 0; mt < 4; mt++)                                  \
        _Pragma("unroll") for (int nt = 0; nt < 4; nt++)                              \
            acc[mt][nt] = (f32x4){0.f, 0.f, 0.f, 0.f};                                \
    for (int k0 = 0; k0 < 1024; k0 += 32) {                                           \
        __syncthreads();                                                              \
        _Pragma("unroll") for (int j = 0; j < 2; j++) {                               \
            int idx = t + j * 256;                                                    \
            int row = idx >> 2, kc = (idx & 3) * 8;                                   \
            *(uint4*)&Ash[row * GLD + kc] = *(const uint4*)(Ah + (size_t)(m0 + row) * 1024 + k0 + kc); \
            *(uint4*)&Asl[row * GLD + kc] = *(const uint4*)(Al + (size_t)(m0 + row) * 1024 + k0 + kc); \
            *(uint4*)&Bsh[row * GLD + kc] = *(const uint4*)(Bh + (size_t)(n0 + row) * 1024 + k0 + kc); \
            *(uint4*)&Bsl[row * GLD + kc] = *(const uint4*)(Bl + (size_t)(n0 + row) * 1024 + k0 + kc); \
        }                                                                             \
        __syncthreads();                                                              \
        bf16x8 ah[4], al[4], bh[4], bl[4];                                            \
        _Pragma("unroll") for (int mt = 0; mt < 4; mt++) {                            \
            ah[mt] = *(const bf16x8*)&Ash[(wm * 64 + mt * 16 + l15) * GLD + qd * 8];  \
            al[mt] = *(const bf16x8*)&Asl[(wm * 64 + mt * 16 + l15) * GLD + qd * 8];  \
        }                                                                             \
        _Pragma("unroll") for (int nt = 0; nt < 4; nt++) {                            \
            bh[nt] = *(const bf16x8*)&Bsh[(wn * 64 + nt * 16 + l15) * GLD + qd * 8];  \
            bl[nt] = *(const bf16x8*)&Bsl[(wn * 64 + nt * 16 + l15) * GLD + qd * 8];  \
        }                                                                             \
        _Pragma("unroll") for (int mt = 0; mt < 4; mt++)                              \
            _Pragma("unroll") for (int nt = 0; nt < 4; nt++) {                        \
                acc[mt][nt] = __builtin_amdgcn_mfma_f32_16x16x32_bf16(ah[mt], bh[nt], acc[mt][nt], 0, 0, 0); \
                acc[mt][nt] = __builtin_amdgcn_mfma_f32_16x16x32_bf16(ah[mt], bl[nt], acc[mt][nt], 0, 0, 0); \
                acc[mt][nt] = __builtin_amdgcn_mfma_f32_16x16x32_bf16(al[mt], bh[nt], acc[mt][nt], 0, 0, 0); \
            }                                                                         \
    }                                                                                 \
    _Pragma("unroll") for (int mt = 0; mt < 4; mt++)                                  \
        _Pragma("unroll") for (int nt = 0; nt < 4; nt++) {                            \
            int gn = n0 + wn * 64 + nt * 16 + l15;                                    \
            _Pragma("unroll") for (int r = 0; r < 4; r++) {                           \
                int gm = m0 + wm * 64 + mt * 16 + qd * 4 + r;                         \
                float vv = acc[mt][nt][r];                                            \
                EPILOGUE                                                              \
            }                                                                         \
        }

__global__ __launch_bounds__(256) void gemm_split_qkv_k(
    const bf16* __restrict__ Ah, const bf16* __restrict__ Al,
    const bf16* __restrict__ Bqh, const bf16* __restrict__ Bql,
    const bf16* __restrict__ Bkh, const bf16* __restrict__ Bkl,
    const bf16* __restrict__ Bvh, const bf16* __restrict__ Bvl,
    bf16* Cqh, bf16* Cql, bf16* Ckh, bf16* Ckl, bf16* Cvh, bf16* Cvl) {
    int z = blockIdx.z;
    const bf16* Bh = (z == 0) ? Bqh : (z == 1) ? Bkh : Bvh;
    const bf16* Bl = (z == 0) ? Bql : (z == 1) ? Bkl : Bvl;
    bf16* Ch = (z == 0) ? Cqh : (z == 1) ? Ckh : Cvh;
    bf16* Cl = (z == 0) ? Cql : (z == 1) ? Ckl : Cvl;
    GEMM_SPLIT_BODY({
        bf16 hi = (bf16)vv;
        Ch[(size_t)gm * D_ + gn] = hi;
        Cl[(size_t)gm * D_ + gn] = (bf16)(vv - (float)hi);
    })
}

__global__ __launch_bounds__(256) void gemm_split_wo_k(
    const bf16* __restrict__ Ah, const bf16* __restrict__ Al,
    const bf16* __restrict__ Bh, const bf16* __restrict__ Bl,
    float* __restrict__ C, const float* __restrict__ X) {
    GEMM_SPLIT_BODY({
        C[(size_t)gm * D_ + gn] = X[(size_t)gm * D_ + gn] + vv;
    })
}

// ---------------------------------------------------------------------------
// Split-bf16 MFMA flash attention. Block = (qt, h, b): 64 q-rows, 4 waves,
// wave w owns q-rows w*16..w*16+15. dh=64. Online softmax in C layout.
// ---------------------------------------------------------------------------
#define AP 72

__global__ __launch_bounds__(256) void attn_mfma_k(
    const bf16* __restrict__ qhp, const bf16* __restrict__ qlp,
    const bf16* __restrict__ khp, const bf16* __restrict__ klp,
    const bf16* __restrict__ vhp, const bf16* __restrict__ vlp,
    bf16* __restrict__ aoh, bf16* __restrict__ aol) {
    int qt = blockIdx.x, h = blockIdx.y, b = blockIdx.z;
    __shared__ bf16 Ksh[64 * AP], Ksl[64 * AP], VTh[64 * AP], VTl[64 * AP];
    __shared__ bf16 Ph[4][16 * AP], Pl[4][16 * AP];
    int t = threadIdx.x, wv = t >> 6, ln = t & 63, l15 = ln & 15, qd = ln >> 4;

    bf16x8 aqh[2], aql[2];
    {
        size_t qb = ((size_t)(b * S_ + qt * 64 + wv * 16 + l15)) * D_ + h * 64 + qd * 8;
        aqh[0] = *(const bf16x8*)(qhp + qb);
        aqh[1] = *(const bf16x8*)(qhp + qb + 32);
        aql[0] = *(const bf16x8*)(qlp + qb);
        aql[1] = *(const bf16x8*)(qlp + qb + 32);
    }
    f32x4 oacc[4];
    float mrow[4], lrow[4];
#pragma unroll
    for (int i = 0; i < 4; i++) {
        oacc[i] = (f32x4){0.f, 0.f, 0.f, 0.f};
        mrow[i] = -1e30f; lrow[i] = 0.0f;
    }

    for (int kt = 0; kt <= qt; kt++) {
        __syncthreads();
#pragma unroll
        for (int j = 0; j < 2; j++) {
            int idx = t + j * 256;
            int row = idx >> 3, ch = (idx & 7) * 8;
            size_t g = ((size_t)(b * S_ + kt * 64 + row)) * D_ + h * 64 + ch;
            *(uint4*)&Ksh[row * AP + ch] = *(const uint4*)(khp + g);
            *(uint4*)&Ksl[row * AP + ch] = *(const uint4*)(klp + g);
            bf16x8 vvh = *(const bf16x8*)(vhp + g);
            bf16x8 vvl = *(const bf16x8*)(vlp + g);
#pragma unroll
            for (int jj = 0; jj < 8; jj++) {
                VTh[(ch + jj) * AP + row] = vvh[jj];
                VTl[(ch + jj) * AP + row] = vvl[jj];
            }
        }
        __syncthreads();

        f32x4 sacc[4];
#pragma unroll
        for (int nt = 0; nt < 4; nt++) sacc[nt] = (f32x4){0.f, 0.f, 0.f, 0.f};
#pragma unroll
        for (int ks = 0; ks < 2; ks++) {
#pragma unroll
            for (int nt = 0; nt < 4; nt++) {
                bf16x8 bh = *(const bf16x8*)&Ksh[(nt * 16 + l15) * AP + ks * 32 + qd * 8];
                bf16x8 bl = *(const bf16x8*)&Ksl[(nt * 16 + l15) * AP + ks * 32 + qd * 8];
                sacc[nt] = __builtin_amdgcn_mfma_f32_16x16x32_bf16(aqh[ks], bh, sacc[nt], 0, 0, 0);
                sacc[nt] = __builtin_amdgcn_mfma_f32_16x16x32_bf16(aqh[ks], bl, sacc[nt], 0, 0, 0);
                sacc[nt] = __builtin_amdgcn_mfma_f32_16x16x32_bf16(aql[ks], bh, sacc[nt], 0, 0, 0);
            }
        }
        bool diag = (kt == qt);
#pragma unroll
        for (int r = 0; r < 4; r++) {
            float s0[4];
#pragma unroll
            for (int nt = 0; nt < 4; nt++) {
                s0[nt] = sacc[nt][r] * 0.125f;
                if (diag && (nt * 16 + l15) > (wv * 16 + qd * 4 + r)) s0[nt] = -1e30f;
            }
            float vmax = fmaxf(fmaxf(s0[0], s0[1]), fmaxf(s0[2], s0[3]));
            for (int off = 1; off < 16; off <<= 1) vmax = fmaxf(vmax, __shfl_xor(vmax, off));
            float mnew = fmaxf(mrow[r], vmax);
            float alpha = expf(mrow[r] - mnew);
            float p[4], rs = 0.0f;
#pragma unroll
            for (int nt = 0; nt < 4; nt++) { p[nt] = expf(s0[nt] - mnew); rs += p[nt]; }
            for (int off = 1; off < 16; off <<= 1) rs += __shfl_xor(rs, off);
            lrow[r] = lrow[r] * alpha + rs;
            mrow[r] = mnew;
#pragma unroll
            for (int nt = 0; nt < 4; nt++) oacc[nt][r] *= alpha;
            int prow = qd * 4 + r;
#pragma unroll
            for (int nt = 0; nt < 4; nt++) {
                bf16 hi = (bf16)p[nt];
                Ph[wv][prow * AP + nt * 16 + l15] = hi;
                Pl[wv][prow * AP + nt * 16 + l15] = (bf16)(p[nt] - (float)hi);
            }
        }
        // PV: same-wave LDS RAW (in-order DS pipe), no barrier needed.
#pragma unroll
        for (int ks2 = 0; ks2 < 2; ks2++) {
            bf16x8 aph = *(const bf16x8*)&Ph[wv][l15 * AP + ks2 * 32 + qd * 8];
            bf16x8 apl = *(const bf16x8*)&Pl[wv][l15 * AP + ks2 * 32 + qd * 8];
#pragma unroll
            for (int nt = 0; nt < 4; nt++) {
                bf16x8 bvh = *(const bf16x8*)&VTh[(nt * 16 + l15) * AP + ks2 * 32 + qd * 8];
                bf16x8 bvl = *(const bf16x8*)&VTl[(nt * 16 + l15) * AP + ks2 * 32 + qd * 8];
                oacc[nt] = __builtin_amdgcn_mfma_f32_16x16x32_bf16(aph, bvh, oacc[nt], 0, 0, 0);
                oacc[nt] = __builtin_amdgcn_mfma_f32_16x16x32_bf16(aph, bvl, oacc[nt], 0, 0, 0);
                oacc[nt] = __builtin_amdgcn_mfma_f32_16x16x32_bf16(apl, bvh, oacc[nt], 0, 0, 0);
            }
        }
    }

#pragma unroll
    for (int r = 0; r < 4; r++) {
        float inv = 1.0f / lrow[r];
        size_t rowa = ((size_t)(b * S_ + qt * 64 + wv * 16 + qd * 4 + r)) * D_ + h * 64;
#pragma unroll
        for (int nt = 0; nt < 4; nt++) {
            float o = oacc[nt][r] * inv;
            bf16 hi = (bf16)o;
            aoh[rowa + nt * 16 + l15] = hi;
            aol[rowa + nt * 16 + l15] = (bf16)(o - (float)hi);
        }
    }
}

// ---------------------------------------------------------------------------
// Router: 4 tokens/block (wave each). fp32 logits -> softmax -> top2.
// ---------------------------------------------------------------------------
__global__ __launch_bounds__(256) void router_k(const float* __restrict__ h,
                                                const float* __restrict__ rw,
                                                int* __restrict__ tidx,
                                                float* __restrict__ tgate,
                                                int* __restrict__ ecnt,
                                                float* __restrict__ psum) {
    int wv = threadIdx.x >> 6, ln = threadIdx.x & 63;
    int tok = blockIdx.x * 4 + wv;
    const float* hr = h + (size_t)tok * D_;
    float acc[NE];
#pragma unroll
    for (int e = 0; e < NE; e++) acc[e] = 0.0f;
    int base = ln * 16;
#pragma unroll
    for (int c = 0; c < 4; c++) {
        float4 hv = *(const float4*)(hr + base + c * 4);
        const float* rp = rw + (size_t)(base + c * 4) * NE;
        float hx[4] = {hv.x, hv.y, hv.z, hv.w};
#pragma unroll
        for (int jj = 0; jj < 4; jj++)
#pragma unroll
            for (int e = 0; e < NE; e++)
                acc[e] = fmaf(hx[jj], rp[jj * NE + e], acc[e]);
    }
#pragma unroll
    for (int e = 0; e < NE; e++)
        for (int off = 32; off; off >>= 1) acc[e] += __shfl_down(acc[e], off);

    __shared__ float pb[4][NE];
    if (ln == 0) {
        float mx = acc[0];
#pragma unroll
        for (int e = 1; e < NE; e++) mx = fmaxf(mx, acc[e]);
        float p[NE], ssum = 0.0f;
#pragma unroll
        for (int e = 0; e < NE; e++) { p[e] = expf(acc[e] - mx); ssum += p[e]; }
        float inv = 1.0f / ssum;
#pragma unroll
        for (int e = 0; e < NE; e++) p[e] *= inv;
        int i0 = 0; float b0 = p[0];
#pragma unroll
        for (int e = 1; e < NE; e++) if (p[e] > b0) { b0 = p[e]; i0 = e; }
        int i1 = -1; float b1v = -1.0f;
#pragma unroll
        for (int e = 0; e < NE; e++) if (e != i0 && p[e] > b1v) { b1v = p[e]; i1 = e; }
        tidx[tok * 2] = i0; tidx[tok * 2 + 1] = i1;
        tgate[tok * 2] = b0; tgate[tok * 2 + 1] = b1v;
        atomicAdd(&ecnt[i0], 1);
        atomicAdd(&ecnt[i1], 1);
#pragma unroll
        for (int e = 0; e < NE; e++) pb[wv][e] = p[e];
    }
    __syncthreads();
    if (threadIdx.x < NE) {
        float s2 = pb[0][threadIdx.x] + pb[1][threadIdx.x] + pb[2][threadIdx.x] + pb[3][threadIdx.x];
        atomicAdd(&psum[threadIdx.x], s2);
    }
}

__global__ void passb_k(const int* __restrict__ ecnt, const float* __restrict__ psum,
                        int* __restrict__ eoffp, int* __restrict__ ecnt2,
                        float* __restrict__ out_tail) {
    if (threadIdx.x == 0) {
        int off = 0; float loss = 0.0f;
        for (int e = 0; e < NE; e++) {
            eoffp[e] = off;
            int c = ecnt[e];
            off += (c + 127) & ~127;
            loss += (c * (1.0f / 4096.0f)) * (psum[e] * (1.0f / 2048.0f));
            out_tail[1 + e] = (float)c;
            ecnt2[e] = 0;
        }
        eoffp[NE] = off;
        out_tail[0] = 8.0f * loss;
    }
}

__global__ __launch_bounds__(256) void scatter_k(const int* __restrict__ tidx,
                                                 const float* __restrict__ tgate,
                                                 const int* __restrict__ eoffp,
                                                 int* __restrict__ ecnt2,
                                                 int* __restrict__ stok,
                                                 float* __restrict__ sgate) {
    int tok = blockIdx.x * 256 + threadIdx.x;
    for (int k = 0; k < 2; k++) {
        int e = tidx[tok * 2 + k];
        int pos = eoffp[e] + atomicAdd(&ecnt2[e], 1);
        stok[pos] = tok;
        sgate[pos] = tgate[tok * 2 + k];
    }
}

// ---------------------------------------------------------------------------
// MoE MFMA GEMMs (plain bf16): 128x128 tile, BK=32, 4 waves 2x2.
// ---------------------------------------------------------------------------
#define MLD 40

__global__ __launch_bounds__(256) void moe_gemm1_k(const bf16* __restrict__ hB,
                                                   const bf16* __restrict__ w1t,
                                                   const float* __restrict__ b1,
                                                   const int* __restrict__ eoffp,
                                                   const int* __restrict__ stok,
                                                   bf16* __restrict__ act) {
    int m0 = blockIdx.x * 128, n0 = blockIdx.y * 128;
    if (m0 >= eoffp[NE]) return;
    int e = 0;
#pragma unroll
    for (int i = 1; i < NE; i++) if (m0 >= eoffp[i]) e = i;

    __shared__ bf16 As[128 * MLD];
    __shared__ bf16 Bs[128 * MLD];
    __shared__ int tok_l[128];
    int t = threadIdx.x;
    if (t < 128) tok_l[t] = stok[m0 + t];

    int wv = t >> 6, ln = t & 63;
    int wm = wv >> 1, wn = wv & 1;
    int lane15 = ln & 15, quad = ln >> 4;
    f32x4 acc[4][4];
#pragma unroll
    for (int mt = 0; mt < 4; mt++)
#pragma unroll
        for (int nt = 0; nt < 4; nt++) acc[mt][nt] = (f32x4){0.f, 0.f, 0.f, 0.f};

    const bf16* Bbase = w1t + ((size_t)e * FF_ + n0) * D_;

    for (int k0 = 0; k0 < D_; k0 += 32) {
        __syncthreads();
#pragma unroll
        for (int j = 0; j < 2; j++) {
            int idx = t + j * 256;
            int row = idx >> 2, kc = (idx & 3) * 8;
            uint4 av = *(const uint4*)(hB + (size_t)tok_l[row] * D_ + k0 + kc);
            *(uint4*)&As[row * MLD + kc] = av;
            uint4 bv = *(const uint4*)(Bbase + (size_t)row * D_ + k0 + kc);
            *(uint4*)&Bs[row * MLD + kc] = bv;
        }
        __syncthreads();
        bf16x8 af[4], bfr[4];
#pragma unroll
        for (int mt = 0; mt < 4; mt++)
            af[mt] = *(const bf16x8*)&As[(wm * 64 + mt * 16 + lane15) * MLD + quad * 8];
#pragma unroll
        for (int nt = 0; nt < 4; nt++)
            bfr[nt] = *(const bf16x8*)&Bs[(wn * 64 + nt * 16 + lane15) * MLD + quad * 8];
#pragma unroll
        for (int mt = 0; mt < 4; mt++)
#pragma unroll
            for (int nt = 0; nt < 4; nt++)
                acc[mt][nt] = __builtin_amdgcn_mfma_f32_16x16x32_bf16(af[mt], bfr[nt], acc[mt][nt], 0, 0, 0);
    }

    const float* b1e = b1 + (size_t)e * FF_;
#pragma unroll
    for (int mt = 0; mt < 4; mt++)
#pragma unroll
        for (int nt = 0; nt < 4; nt++) {
            int gn = n0 + wn * 64 + nt * 16 + lane15;
            float bias = b1e[gn];
#pragma unroll
            for (int r = 0; r < 4; r++) {
                int gm = m0 + wm * 64 + mt * 16 + quad * 4 + r;
                float vv = acc[mt][nt][r] + bias;
                act[(size_t)gm * FF_ + gn] = (bf16)gelu_f(vv);
            }
        }
}

__global__ __launch_bounds__(256) void moe_gemm2_k(const bf16* __restrict__ act,
                                                   const bf16* __restrict__ w2t,
                                                   const float* __restrict__ b2,
                                                   const int* __restrict__ eoffp,
                                                   const int* __restrict__ stok,
                                                   const float* __restrict__ sgate,
                                                   float* __restrict__ out) {
    int m0 = blockIdx.x * 128, n0 = blockIdx.y * 128;
    if (m0 >= eoffp[NE]) return;
    int e = 0;
#pragma unroll
    for (int i = 1; i < NE; i++) if (m0 >= eoffp[i]) e = i;

    __shared__ bf16 As[128 * MLD];
    __shared__ bf16 Bs[128 * MLD];
    __shared__ int tok_l[128];
    __shared__ float gate_l[128];
    int t = threadIdx.x;
    if (t < 128) { tok_l[t] = stok[m0 + t]; gate_l[t] = sgate[m0 + t]; }

    int wv = t >> 6, ln = t & 63;
    int wm = wv >> 1, wn = wv & 1;
    int lane15 = ln & 15, quad = ln >> 4;
    f32x4 acc[4][4];
#pragma unroll
    for (int mt = 0; mt < 4; mt++)
#pragma unroll
        for (int nt = 0; nt < 4; nt++) acc[mt][nt] = (f32x4){0.f, 0.f, 0.f, 0.f};

    const bf16* Bbase = w2t + ((size_t)e * D_ + n0) * FF_;

    for (int k0 = 0; k0 < FF_; k0 += 32) {
        __syncthreads();
#pragma unroll
        for (int j = 0; j < 2; j++) {
            int idx = t + j * 256;
            int row = idx >> 2, kc = (idx & 3) * 8;
            uint4 av = *(const uint4*)(act + (size_t)(m0 + row) * FF_ + k0 + kc);
            *(uint4*)&As[row * MLD + kc] = av;
            uint4 bv = *(const uint4*)(Bbase + (size_t)row * FF_ + k0 + kc);
            *(uint4*)&Bs[row * MLD + kc] = bv;
        }
        __syncthreads();
        bf16x8 af[4], bfr[4];
#pragma unroll
        for (int mt = 0; mt < 4; mt++)
            af[mt] = *(const bf16x8*)&As[(wm * 64 + mt * 16 + lane15) * MLD + quad * 8];
#pragma unroll
        for (int nt = 0; nt < 4; nt++)
            bfr[nt] = *(const bf16x8*)&Bs[(wn * 64 + nt * 16 + lane15) * MLD + quad * 8];
#pragma unroll
        for (int mt = 0; mt < 4; mt++)
#pragma unroll
            for (int nt = 0; nt < 4; nt++)
                acc[mt][nt] = __builtin_amdgcn_mfma_f32_16x16x32_bf16(af[mt], bfr[nt], acc[mt][nt], 0, 0, 0);
    }

    const float* b2e = b2 + (size_t)e * D_;
#pragma unroll
    for (int mt = 0; mt < 4; mt++)
#pragma unroll
        for (int nt = 0; nt < 4; nt++) {
            int gn = n0 + wn * 64 + nt * 16 + lane15;
            float bias = b2e[gn];
#pragma unroll
            for (int r = 0; r < 4; r++) {
                int lm = wm * 64 + mt * 16 + quad * 4 + r;
                int tok = tok_l[lm];
                float g = gate_l[lm];
                atomicAdd(out + (size_t)tok * D_ + gn, g * (acc[mt][nt][r] + bias));
            }
        }
}

// ---------------------------------------------------------------------------
extern "C" void kernel_launch(void* const* d_in, const int* in_sizes, int n_in,
                              void* d_out, int out_size, void* d_ws, size_t ws_size,
                              hipStream_t stream) {
    const float* x   = (const float*)d_in[0];
    const float* anw = (const float*)d_in[1];
    const float* wq  = (const float*)d_in[2];
    const float* wk  = (const float*)d_in[3];
    const float* wv  = (const float*)d_in[4];
    const float* wo  = (const float*)d_in[5];
    const float* mnw = (const float*)d_in[6];
    const float* rw  = (const float*)d_in[7];
    const float* w1  = (const float*)d_in[8];
    const float* b1  = (const float*)d_in[9];
    const float* w2  = (const float*)d_in[10];
    const float* b2  = (const float*)d_in[11];
    float* out = (float*)d_out;

    char* p = (char*)d_ws;
    auto take = [&](size_t n) { char* r = p; p += (n + 255) & ~(size_t)255; return r; };
    bf16* h1h = (bf16*)take((size_t)OUTN * 2);
    bf16* h1l = (bf16*)take((size_t)OUTN * 2);
    bf16* qh  = (bf16*)take((size_t)OUTN * 2);
    bf16* ql  = (bf16*)take((size_t)OUTN * 2);
    bf16* kh  = (bf16*)take((size_t)OUTN * 2);
    bf16* kl  = (bf16*)take((size_t)OUTN * 2);
    bf16* vh  = (bf16*)take((size_t)OUTN * 2);
    bf16* vl  = (bf16*)take((size_t)OUTN * 2);
    bf16* wqth = (bf16*)take((size_t)D_ * D_ * 2);
    bf16* wqtl = (bf16*)take((size_t)D_ * D_ * 2);
    bf16* wkth = (bf16*)take((size_t)D_ * D_ * 2);
    bf16* wktl = (bf16*)take((size_t)D_ * D_ * 2);
    bf16* wvth = (bf16*)take((size_t)D_ * D_ * 2);
    bf16* wvtl = (bf16*)take((size_t)D_ * D_ * 2);
    bf16* woth = (bf16*)take((size_t)D_ * D_ * 2);
    bf16* wotl = (bf16*)take((size_t)D_ * D_ * 2);
    bf16* w1t = (bf16*)take((size_t)NE * FF_ * D_ * 2);
    bf16* w2t = (bf16*)take((size_t)NE * FF_ * D_ * 2);
    bf16* act = (bf16*)take((size_t)CAP * FF_ * 2);
    int*   tidx  = (int*)take(NTOK * 2 * 4);
    float* tgate = (float*)take(NTOK * 2 * 4);
    int*   ecnt  = (int*)take(64);
    int*   ecnt2 = (int*)take(64);
    float* psum  = (float*)take(64);
    int*   eoffp = (int*)take(64);
    int*   stok  = (int*)take(CAP * 4);
    float* sgate = (float*)take(CAP * 4);

    // aliases over dead buffers (h1 dead after QKV gemm; q/k dead after attn)
    bf16*  aoh = h1h;
    bf16*  aol = h1l;
    float* h_f = (float*)qh;   // spans qh+ql (8 MB)
    bf16*  h_b = kh;

    hipMemsetAsync(ecnt, 0, NE * 4, stream);
    hipMemsetAsync(psum, 0, NE * 4, stream);
    hipMemsetAsync(stok, 0, CAP * 4, stream);
    hipMemsetAsync(sgate, 0, CAP * 4, stream);

    // weight transposes
    trans_split_k<<<dim3(32, 32, 4), 256, 0, stream>>>(wq, wk, wv, wo,
        wqth, wqtl, wkth, wktl, wvth, wvtl, woth, wotl);
    transpose_cast_k<<<dim3(FF_ / 32, D_ / 32, NE), 256, 0, stream>>>(w1, w1t, D_, FF_);
    transpose_cast_k<<<dim3(D_ / 32, FF_ / 32, NE), 256, 0, stream>>>(w2, w2t, FF_, D_);

    // attention path (split-bf16 MFMA, fp32-fidelity for router)
    rmsnorm_k<<<NTOK, 256, 0, stream>>>(x, anw, nullptr, h1h, h1l);
    gemm_split_qkv_k<<<dim3(16, 8, 3), 256, 0, stream>>>(h1h, h1l,
        wqth, wqtl, wkth, wktl, wvth, wvtl,
        qh, ql, kh, kl, vh, vl);
    attn_mfma_k<<<dim3(16, 16, 2), 256, 0, stream>>>(qh, ql, kh, kl, vh, vl, aoh, aol);
    gemm_split_wo_k<<<dim3(16, 8), 256, 0, stream>>>(aoh, aol, woth, wotl, out, x);

    // MoE
    rmsnorm_k<<<NTOK, 256, 0, stream>>>(out, mnw, h_f, h_b, nullptr);
    router_k<<<NTOK / 4, 256, 0, stream>>>(h_f, rw, tidx, tgate, ecnt, psum);
    passb_k<<<1, 64, 0, stream>>>(ecnt, psum, eoffp, ecnt2, out + OUTN);
    scatter_k<<<NTOK / 256, 256, 0, stream>>>(tidx, tgate, eoffp, ecnt2, stok, sgate);
    moe_gemm1_k<<<dim3(CAP / 128, FF_ / 128), 256, 0, stream>>>(h_b, w1t, b1, eoffp, stok, act);
    moe_gemm2_k<<<dim3(CAP / 128, D_ / 128), 256, 0, stream>>>(act, w2t, b2, eoffp, stok, sgate, out);
}